// Round 2
// baseline (6583.937 us; speedup 1.0000x reference)
//
#include <hip/hip_runtime.h>
#include <math.h>

#define NRES 1024
#define HH 8
#define CC 48
#define CZF 128
#define NPAIRS 1048576

// ---------------------------------------------------------------------------
// K1: raw projections  raw[n][1632] = s[n][:] @ [wq|wkv|wkvp] + bias
// grid 512 = 128 n-tiles(8 rows) x 4 col-chunks(408)
__global__ __launch_bounds__(256) void k_proj(
    const float* __restrict__ s,
    const float* __restrict__ wq, const float* __restrict__ bq,
    const float* __restrict__ wkv, const float* __restrict__ bkv,
    const float* __restrict__ wkvp, const float* __restrict__ bkvp,
    float* __restrict__ raw)
{
  int bb = blockIdx.x;
  int n0 = (bb >> 2) * 8;
  int ch = bb & 3;
  int t = threadIdx.x;
  const float* srow = s + (size_t)n0 * 384;   // uniform reads -> scalar loads
  for (int ci = 0; ci < 2; ci++) {
    int local = ci * 256 + t;
    if (local >= 408) break;
    int col = ch * 408 + local;
    const float* w; int ld; float bias;
    if (col < 384)       { w = wq  + col;          ld = 384; bias = bq[col]; }
    else if (col < 1152) { w = wkv + (col - 384);  ld = 768; bias = bkv[col - 384]; }
    else                 { w = wkvp + (col - 1152); ld = 480; bias = bkvp[col - 1152]; }
    float acc[8];
#pragma unroll
    for (int r = 0; r < 8; r++) acc[r] = bias;
    for (int k = 0; k < 384; k++) {
      float wv = w[(size_t)k * ld];
#pragma unroll
      for (int r = 0; r < 8; r++) acc[r] = fmaf(srow[r * 384 + k], wv, acc[r]);
    }
#pragma unroll
    for (int r = 0; r < 8; r++) raw[(size_t)(n0 + r) * 1632 + col] = acc[r];
  }
}

// ---------------------------------------------------------------------------
// K1b: rotation + scaling + layout scatter.  grid 1024 (one block per n)
__global__ __launch_bounds__(256) void k_scatter(
    const float* __restrict__ raw, const float* __restrict__ rot,
    const float* __restrict__ gw,
    float* __restrict__ qp, float* __restrict__ kp, float* __restrict__ V2)
{
  int n = blockIdx.x, t = threadIdx.x;
  __shared__ float rsh[1632];
  __shared__ float hwsh[16];
  for (int i = t; i < 1632; i += 256) rsh[i] = raw[(size_t)n * 1632 + i];
  if (t < 16) hwsh[t] = log1pf(expf(gw[t])) * 0.25f;
  __syncthreads();
  float r00 = rot[n*9+0], r01 = rot[n*9+1], r02 = rot[n*9+2];
  float r10 = rot[n*9+3], r11 = rot[n*9+4], r12 = rot[n*9+5];
  float r20 = rot[n*9+6], r21 = rot[n*9+7], r22 = rot[n*9+8];
  for (int idx = t; idx < 768; idx += 256) {
    int isK = idx >= 384;
    int rem = idx - (isK ? 384 : 0);
    int h = rem / 48, gi = rem % 48, g = gi / 3, ii = gi % 3;
    int cb = isK ? (384 + h * 96 + g * 3) : (h * 48 + g * 3);
    float x = rsh[cb], y = rsh[cb + 1], zz = rsh[cb + 2];
    float d0 = r00 * x + r01 * y + r02 * zz;
    float d1 = r10 * x + r11 * y + r12 * zz;
    float d2 = r20 * x + r21 * y + r22 * zz;
    float val = (ii == 0) ? d0 : (ii == 1 ? d1 : d2);
    if (!isK) {
      val *= hwsh[g] * 0.57735026919f;           // hw[g] / sqrt(3)
      qp[(size_t)((h << 10) + n) * 48 + gi] = val;
    } else {
      kp[(size_t)((h << 10) + n) * 48 + gi] = val;
    }
  }
  for (int idx = t; idx < 768; idx += 256) {
    int h = idx / 96, c = idx % 96;
    float val = 0.f;
    if (c < 48) val = rsh[384 + h * 96 + 48 + c];
    else if (c < 84) {
      int pc = c - 48, pp = pc / 3, j = pc % 3;
      val = rsh[1152 + j * 160 + h * 20 + 8 + pp];
    }
    V2[(size_t)((h << 10) + n) * 96 + c] = val;
  }
}

// ---------------------------------------------------------------------------
// pack 2 floats -> 2 bf16 (RNE) in one uint
__device__ inline unsigned int pk_bf2(float lo, float hi) {
  unsigned int a = __float_as_uint(lo), b = __float_as_uint(hi);
  a += 0x7fffu + ((a >> 16) & 1u);
  b += 0x7fffu + ((b >> 16) & 1u);
  return (a >> 16) | (b & 0xffff0000u);
}

// ---------------------------------------------------------------------------
// K2: fused bias + pair_z projection.  One pass over z produces BOTH
//   S[h][pair]  = sqrt(1/3)*(z[pair]@wb[:,h] + bb[h]) + INF*(mask_n*mask_m-1)
//   PZ[pair][d] = bf16(z[pair]@wdz[:,d] + bdz[d])      (d in [0,32))
// 40 outs; weights in LDS with bank-permuted rows; G=3 pairs/thread
// (each weight b128 feeds 12 FMA). grid 5462 x 256, 192 pairs/block.
__global__ __launch_bounds__(256) void k_biaspz(
    const float* __restrict__ z, const float* __restrict__ wb,
    const float* __restrict__ wdz,
    const float* __restrict__ bb, const float* __restrict__ bdz,
    const float* __restrict__ mask,
    float* __restrict__ S, unsigned int* __restrict__ PZ)
{
  __shared__ float wsh[128 * 44];   // row rc=(c&31)*4|(c>>5), 40 outs + pad 4
  __shared__ float bbsh[8];
  __shared__ float bdzsh[32];
  int t = threadIdx.x;
  for (int idx = t; idx < 1280; idx += 256) {
    int c = idx / 10, o4 = idx % 10;
    int rc = ((c & 31) << 2) | (c >> 5);
    float4 v;
    if (o4 < 2) v = *(const float4*)(wb + c * 8 + o4 * 4);
    else        v = *(const float4*)(wdz + c * 32 + (o4 - 2) * 4);
    *(float4*)&wsh[rc * 44 + o4 * 4] = v;
  }
  if (t < 8)  bbsh[t] = bb[t];
  if (t < 32) bdzsh[t] = bdz[t];
  __syncthreads();
  int q = t & 3, rr = t >> 2;          // q: c-quarter (32c), rr: 0..63
  size_t pair0 = (size_t)blockIdx.x * 192;
  size_t p0 = pair0 + rr, p1 = pair0 + 64 + rr, p2 = pair0 + 128 + rr;
  bool v1 = p1 < NPAIRS, v2 = p2 < NPAIRS;
  if (!v1) p1 = p0;
  if (!v2) p2 = p0;
  float4 acc[3][10];
#pragma unroll
  for (int g = 0; g < 3; g++)
#pragma unroll
    for (int o = 0; o < 10; o++) acc[g][o] = {0.f, 0.f, 0.f, 0.f};
  const float* zq = z + q * 32;
#pragma unroll 2
  for (int i = 0; i < 8; i++) {
    float4 z0 = *(const float4*)(zq + p0 * 128 + i * 4);
    float4 z1 = *(const float4*)(zq + p1 * 128 + i * 4);
    float4 z2 = *(const float4*)(zq + p2 * 128 + i * 4);
#pragma unroll
    for (int j = 0; j < 4; j++) {
      float a0 = (j == 0) ? z0.x : (j == 1) ? z0.y : (j == 2) ? z0.z : z0.w;
      float a1 = (j == 0) ? z1.x : (j == 1) ? z1.y : (j == 2) ? z1.z : z1.w;
      float a2 = (j == 0) ? z2.x : (j == 1) ? z2.y : (j == 2) ? z2.z : z2.w;
      const float* wr = &wsh[((((i * 4 + j) << 2) | q)) * 44];
#pragma unroll
      for (int o = 0; o < 10; o++) {
        float4 w = *(const float4*)(wr + o * 4);
        acc[0][o].x = fmaf(a0, w.x, acc[0][o].x); acc[0][o].y = fmaf(a0, w.y, acc[0][o].y);
        acc[0][o].z = fmaf(a0, w.z, acc[0][o].z); acc[0][o].w = fmaf(a0, w.w, acc[0][o].w);
        acc[1][o].x = fmaf(a1, w.x, acc[1][o].x); acc[1][o].y = fmaf(a1, w.y, acc[1][o].y);
        acc[1][o].z = fmaf(a1, w.z, acc[1][o].z); acc[1][o].w = fmaf(a1, w.w, acc[1][o].w);
        acc[2][o].x = fmaf(a2, w.x, acc[2][o].x); acc[2][o].y = fmaf(a2, w.y, acc[2][o].y);
        acc[2][o].z = fmaf(a2, w.z, acc[2][o].z); acc[2][o].w = fmaf(a2, w.w, acc[2][o].w);
      }
    }
  }
  // butterfly reduce over the 4 q-lanes
#pragma unroll
  for (int g = 0; g < 3; g++)
#pragma unroll
    for (int o = 0; o < 10; o++) {
      float4& a = acc[g][o];
      a.x += __shfl_xor(a.x, 1); a.x += __shfl_xor(a.x, 2);
      a.y += __shfl_xor(a.y, 1); a.y += __shfl_xor(a.y, 2);
      a.z += __shfl_xor(a.z, 1); a.z += __shfl_xor(a.z, 2);
      a.w += __shfl_xor(a.w, 1); a.w += __shfl_xor(a.w, 2);
    }
  const float is3 = 0.57735026919f;
  int h0 = q * 2;
  float bd0 = bdzsh[q * 8 + 0], bd1 = bdzsh[q * 8 + 1];
  float bd2 = bdzsh[q * 8 + 2], bd3 = bdzsh[q * 8 + 3];
  float bd4 = bdzsh[q * 8 + 4], bd5 = bdzsh[q * 8 + 5];
  float bd6 = bdzsh[q * 8 + 6], bd7 = bdzsh[q * 8 + 7];
#pragma unroll
  for (int g = 0; g < 3; g++) {
    if (g == 1 && !v1) continue;
    if (g == 2 && !v2) continue;
    size_t pair = pair0 + (size_t)g * 64 + rr;
    int n = (int)(pair >> 10), m = (int)(pair & 1023);
    float mt = 100000.0f * (mask[n] * mask[m] - 1.0f);
    // b outs: h = 2q, 2q+1 live in acc[g][0..1]
    float4 bsel = (q < 2) ? acc[g][0] : acc[g][1];
    float b0 = (q & 1) ? bsel.z : bsel.x;
    float b1 = (q & 1) ? bsel.w : bsel.y;
    S[(size_t)h0 * 1048576 + pair]       = (b0 + bbsh[h0]) * is3 + mt;
    S[(size_t)(h0 + 1) * 1048576 + pair] = (b1 + bbsh[h0 + 1]) * is3 + mt;
    // pz outs: dims q*8..q*8+8 live in acc[g][2+2q], acc[g][3+2q]
    float4 pa = (q == 0) ? acc[g][2] : (q == 1) ? acc[g][4] : (q == 2) ? acc[g][6] : acc[g][8];
    float4 pb = (q == 0) ? acc[g][3] : (q == 1) ? acc[g][5] : (q == 2) ? acc[g][7] : acc[g][9];
    uint4 pw;
    pw.x = pk_bf2(pa.x + bd0, pa.y + bd1);
    pw.y = pk_bf2(pa.z + bd2, pa.w + bd3);
    pw.z = pk_bf2(pb.x + bd4, pb.y + bd5);
    pw.w = pk_bf2(pb.z + bd6, pb.w + bd7);
    *(uint4*)(PZ + pair * 16 + q * 4) = pw;
  }
}

// ---------------------------------------------------------------------------
// K3: scores + bias + softmax (in-place into S). grid 1024 = 8h x 128 tiles(8 n)
__global__ __launch_bounds__(256) void k_attn(
    const float* __restrict__ qp, const float* __restrict__ kp,
    float* __restrict__ S)
{
  int b = blockIdx.x;
  int h = b >> 7, n0 = (b & 127) * 8;
  int t = threadIdx.x;
  __shared__ float ksh[128 * 52];   // 128 k-rows, stride 52 (pad for banks)
  __shared__ float ssh[8 * 1024];
  int ms = t & 127, nh = t >> 7;
  const float* qbase = qp + (size_t)((h << 10) + n0 + nh * 4) * 48;
  size_t Sbase = (size_t)h * 1048576 + (size_t)n0 * 1024;
  for (int cb = 0; cb < 1024; cb += 128) {
    __syncthreads();
    for (int idx = t; idx < 1536; idx += 256) {
      int r = idx / 12, p = idx % 12;
      float4 f = *(const float4*)(kp + (size_t)((h << 10) + cb + r) * 48 + p * 4);
      *(float4*)&ksh[r * 52 + p * 4] = f;
    }
    __syncthreads();
    int m = cb + ms;
    float a0 = 0.f, a1 = 0.f, a2 = 0.f, a3 = 0.f;
#pragma unroll
    for (int ic = 0; ic < 12; ic++) {
      float4 kf = *(const float4*)&ksh[ms * 52 + ic * 4];
      float4 q0 = *(const float4*)(qbase + 0 * 48 + ic * 4);
      float4 q1 = *(const float4*)(qbase + 1 * 48 + ic * 4);
      float4 q2 = *(const float4*)(qbase + 2 * 48 + ic * 4);
      float4 q3 = *(const float4*)(qbase + 3 * 48 + ic * 4);
      a0 += q0.x * kf.x + q0.y * kf.y + q0.z * kf.z + q0.w * kf.w;
      a1 += q1.x * kf.x + q1.y * kf.y + q1.z * kf.z + q1.w * kf.w;
      a2 += q2.x * kf.x + q2.y * kf.y + q2.z * kf.z + q2.w * kf.w;
      a3 += q3.x * kf.x + q3.y * kf.y + q3.z * kf.z + q3.w * kf.w;
    }
    int rb = nh * 4;
    ssh[(rb + 0) * 1024 + m] = a0 + S[Sbase + (size_t)(rb + 0) * 1024 + m];
    ssh[(rb + 1) * 1024 + m] = a1 + S[Sbase + (size_t)(rb + 1) * 1024 + m];
    ssh[(rb + 2) * 1024 + m] = a2 + S[Sbase + (size_t)(rb + 2) * 1024 + m];
    ssh[(rb + 3) * 1024 + m] = a3 + S[Sbase + (size_t)(rb + 3) * 1024 + m];
  }
  __syncthreads();
  int row = t >> 5, lane = t & 31;
  float* sr = ssh + row * 1024;
  float mx = -1e30f;
  for (int j = lane; j < 1024; j += 32) mx = fmaxf(mx, sr[j]);
#pragma unroll
  for (int o = 16; o >= 1; o >>= 1) mx = fmaxf(mx, __shfl_xor(mx, o, 32));
  float sum = 0.f;
  for (int j = lane; j < 1024; j += 32) {
    float e = __expf(sr[j] - mx);
    sr[j] = e; sum += e;
  }
#pragma unroll
  for (int o = 16; o >= 1; o >>= 1) sum += __shfl_xor(sum, o, 32);
  float inv = 1.0f / sum;
  float* Sout = S + Sbase + (size_t)row * 1024;
  for (int j = lane; j < 1024; j += 32) Sout[j] = sr[j] * inv;
}

// ---------------------------------------------------------------------------
// K4: o / o_pt / norms -> F cols [0..767]. grid 512 = 8h x 64 tiles(16 n)
__global__ __launch_bounds__(256) void k_av(
    const float* __restrict__ S, const float* __restrict__ V2,
    float* __restrict__ F)
{
  int b = blockIdx.x;
  int h = b >> 6, n0 = (b & 63) * 16;
  int t = threadIdx.x;
  __shared__ float asT[1024 * 18];  // [m][nn], stride 18
  __shared__ float fsh[16 * 96];
  size_t Sbase = (size_t)h * 1048576 + (size_t)n0 * 1024;
  for (int idx = t; idx < 16384; idx += 256) {
    int nn = idx >> 10, m = idx & 1023;
    asT[m * 18 + nn] = S[Sbase + (size_t)nn * 1024 + m];
  }
  __syncthreads();
  int np = t >> 5, c4 = t & 31;
  float4 a0 = {0,0,0,0}, a1 = {0,0,0,0};
  if (c4 < 24) {
    const float* vbase = V2 + (size_t)(h << 10) * 96 + c4 * 4;
#pragma unroll 4
    for (int mm = 0; mm < 1024; mm++) {
      float4 vv = *(const float4*)(vbase + (size_t)mm * 96);
      float2 av = *(const float2*)&asT[mm * 18 + np * 2];
      a0.x += av.x * vv.x; a0.y += av.x * vv.y; a0.z += av.x * vv.z; a0.w += av.x * vv.w;
      a1.x += av.y * vv.x; a1.y += av.y * vv.y; a1.z += av.y * vv.z; a1.w += av.y * vv.w;
    }
    *(float4*)&fsh[(np * 2 + 0) * 96 + c4 * 4] = a0;
    *(float4*)&fsh[(np * 2 + 1) * 96 + c4 * 4] = a1;
  }
  __syncthreads();
  for (int idx = t; idx < 768; idx += 256) {
    int nn = idx / 48, c = idx % 48;
    F[(size_t)(n0 + nn) * 1024 + h * 48 + c] = fsh[nn * 96 + c];
  }
  for (int idx = t; idx < 192; idx += 256) {
    int nn = idx / 12, pp = idx % 12;
    float x = fsh[nn * 96 + 48 + pp * 3];
    float y = fsh[nn * 96 + 48 + pp * 3 + 1];
    float zz = fsh[nn * 96 + 48 + pp * 3 + 2];
    size_t base = (size_t)(n0 + nn) * 1024;
    F[base + 384 + h * 12 + pp] = x;
    F[base + 480 + h * 12 + pp] = y;
    F[base + 576 + h * 12 + pp] = zz;
    F[base + 672 + h * 12 + pp] = sqrtf(x * x + y * y + zz * zz + 1e-8f);
  }
}

// ---------------------------------------------------------------------------
// K5': o_pair[n][h][32] = sum_m a[h][n][m] * PZ[n][m][:] -> F cols [768..1024)
// a staged once in LDS; PZ streamed bf16 (fully coalesced). grid 1024.
__global__ __launch_bounds__(256) void k_opair(
    const float* __restrict__ S, const unsigned int* __restrict__ PZ,
    float* __restrict__ F)
{
  int n = blockIdx.x, t = threadIdx.x;
  __shared__ float ash[8192];       // [m][h] stride 8; reused as reduce scratch
  for (int idx = t; idx < 8192; idx += 256) {
    int hh = idx >> 10, m = idx & 1023;
    ash[m * 8 + hh] = S[(size_t)hh * 1048576 + (size_t)n * 1024 + m];
  }
  __syncthreads();
  int d4 = t & 7, mg = (t >> 3) & 7, hs = t >> 6;   // hs uniform per wave
  float4 acc0 = {0,0,0,0}, acc1 = {0,0,0,0};        // h = 2hs, 2hs+1
  const uint2* pzrow = (const uint2*)PZ + (size_t)(n << 10) * 8;
#pragma unroll 4
  for (int k2 = 0; k2 < 128; k2++) {
    int m = k2 * 8 + mg;
    uint2 u = pzrow[m * 8 + d4];
    float f0 = __uint_as_float(u.x << 16);
    float f1 = __uint_as_float(u.x & 0xffff0000u);
    float f2 = __uint_as_float(u.y << 16);
    float f3 = __uint_as_float(u.y & 0xffff0000u);
    float2 av = *(const float2*)&ash[m * 8 + hs * 2];
    acc0.x = fmaf(av.x, f0, acc0.x); acc0.y = fmaf(av.x, f1, acc0.y);
    acc0.z = fmaf(av.x, f2, acc0.z); acc0.w = fmaf(av.x, f3, acc0.w);
    acc1.x = fmaf(av.y, f0, acc1.x); acc1.y = fmaf(av.y, f1, acc1.y);
    acc1.z = fmaf(av.y, f2, acc1.z); acc1.w = fmaf(av.y, f3, acc1.w);
  }
  __syncthreads();   // done reading ash; reuse as scratch
  {
    int ob0 = (hs * 2 + 0) * 32 + d4 * 4;
    int ob1 = (hs * 2 + 1) * 32 + d4 * 4;
    *(float4*)&ash[mg * 256 + ob0] = acc0;
    *(float4*)&ash[mg * 256 + ob1] = acc1;
  }
  __syncthreads();
  {
    float sv = 0.f;
#pragma unroll
    for (int g = 0; g < 8; g++) sv += ash[g * 256 + t];
    F[(size_t)n * 1024 + 768 + t] = sv;
  }
}

// ---------------------------------------------------------------------------
// K6: out = F@wout + bout.  grid 512 (2 n per block)
__global__ __launch_bounds__(256) void k_out(
    const float* __restrict__ F,
    const float* __restrict__ wout, const float* __restrict__ bout,
    float* __restrict__ out)
{
  int n0 = blockIdx.x * 2, t = threadIdx.x;
  __shared__ float fsh[2 * 1024];
  for (int idx = t; idx < 2048; idx += 256)
    fsh[idx] = F[(size_t)n0 * 1024 + idx];
  __syncthreads();
  int j = t & 127, kh = t >> 7;
  float a[3][2];
#pragma unroll
  for (int jj = 0; jj < 3; jj++)
#pragma unroll
    for (int r = 0; r < 2; r++) a[jj][r] = 0.f;
  const float4* f4p = (const float4*)fsh;
  for (int k4 = kh * 128; k4 < kh * 128 + 128; k4++) {
    float4 f0 = f4p[k4];
    float4 f1 = f4p[256 + k4];
    int k = k4 * 4;
#pragma unroll
    for (int u = 0; u < 4; u++) {
      float w0 = wout[(size_t)(k + u) * 384 + j];
      float w1 = wout[(size_t)(k + u) * 384 + j + 128];
      float w2 = wout[(size_t)(k + u) * 384 + j + 256];
      float e0 = (u == 0) ? f0.x : (u == 1) ? f0.y : (u == 2) ? f0.z : f0.w;
      float e1 = (u == 0) ? f1.x : (u == 1) ? f1.y : (u == 2) ? f1.z : f1.w;
      a[0][0] = fmaf(e0, w0, a[0][0]); a[0][1] = fmaf(e1, w0, a[0][1]);
      a[1][0] = fmaf(e0, w1, a[1][0]); a[1][1] = fmaf(e1, w1, a[1][1]);
      a[2][0] = fmaf(e0, w2, a[2][0]); a[2][1] = fmaf(e1, w2, a[2][1]);
    }
  }
  __syncthreads();   // done reading fsh; reuse as reduction scratch
  if (kh == 1) {
#pragma unroll
    for (int jj = 0; jj < 3; jj++)
#pragma unroll
      for (int r = 0; r < 2; r++)
        fsh[(jj * 2 + r) * 128 + j] = a[jj][r];
  }
  __syncthreads();
  if (kh == 0) {
#pragma unroll
    for (int jj = 0; jj < 3; jj++)
#pragma unroll
      for (int r = 0; r < 2; r++) {
        float v = a[jj][r] + fsh[(jj * 2 + r) * 128 + j] + bout[jj * 128 + j];
        out[(size_t)(n0 + r) * 384 + jj * 128 + j] = v;
      }
  }
}

// ---------------------------------------------------------------------------
extern "C" void kernel_launch(void* const* d_in, const int* in_sizes, int n_in,
                              void* d_out, int out_size, void* d_ws, size_t ws_size,
                              hipStream_t stream) {
  const float* s    = (const float*)d_in[0];
  const float* z    = (const float*)d_in[1];
  const float* rot  = (const float*)d_in[2];
  const float* mask = (const float*)d_in[3];
  const float* wq   = (const float*)d_in[4];
  const float* bq   = (const float*)d_in[5];
  const float* wkv  = (const float*)d_in[6];
  const float* bkv  = (const float*)d_in[7];
  const float* wkvp = (const float*)d_in[8];
  const float* bkvp = (const float*)d_in[9];
  const float* wb   = (const float*)d_in[10];
  const float* bb   = (const float*)d_in[11];
  const float* wdz  = (const float*)d_in[12];
  const float* bdz  = (const float*)d_in[13];
  const float* wout = (const float*)d_in[14];
  const float* bout = (const float*)d_in[15];
  const float* gw   = (const float*)d_in[16];
  float* out = (float*)d_out;

  float* ws  = (float*)d_ws;
  float* raw = ws;                       // 1024*1632
  float* qp  = raw + 1024 * 1632;        // 8*1024*48
  float* kp  = qp + 393216;              // 8*1024*48
  float* V2  = kp + 393216;              // 8*1024*96
  float* S   = V2 + 786432;              // 8*1024*1024
  float* PZf = S + 8388608;              // 1024*1024*16 (uint32 slots)
  float* F   = PZf + 16777216;           // 1024*1024
  unsigned int* PZ = (unsigned int*)PZf;

  k_proj<<<512, 256, 0, stream>>>(s, wq, bq, wkv, bkv, wkvp, bkvp, raw);
  k_scatter<<<1024, 256, 0, stream>>>(raw, rot, gw, qp, kp, V2);
  k_biaspz<<<5462, 256, 0, stream>>>(z, wb, wdz, bb, bdz, mask, S, PZ);
  k_attn<<<1024, 256, 0, stream>>>(qp, kp, S);
  k_av<<<512, 256, 0, stream>>>(S, V2, F);
  k_opair<<<1024, 256, 0, stream>>>(S, PZ, F);
  k_out<<<512, 256, 0, stream>>>(F, wout, bout, out);
}